// Round 1
// baseline (696.408 us; speedup 1.0000x reference)
//
#include <hip/hip_runtime.h>
#include <hip/hip_bf16.h>
#include <stdint.h>

#define M_DIM 4096
#define N_DIM 11008
#define K_DIM 4096
#define BM 128
#define BN 128
#define BK 64

typedef float f32x4 __attribute__((ext_vector_type(4)));
typedef __bf16 bf16x8 __attribute__((ext_vector_type(8)));
typedef unsigned short u16x8 __attribute__((ext_vector_type(8)));
typedef unsigned short u16x4 __attribute__((ext_vector_type(4)));

__device__ __forceinline__ unsigned short f2bf(float f) {
    union { float f; unsigned u; } v; v.f = f;
    return (unsigned short)((v.u + 0x7FFFu + ((v.u >> 16) & 1u)) >> 16);
}

__global__ void __launch_bounds__(256) gptq_gemm_kernel(
    const float* __restrict__ X, const int* __restrict__ QW,
    const int* __restrict__ QZ, const float* __restrict__ SC,
    const float* __restrict__ BIAS, float* __restrict__ OUT)
{
    // A: [128 rows][64 bf16] swizzled, bytes [0, 16384)
    // B: [128 n][64 k bf16] swizzled, bytes [16384, 32768)
    __shared__ __align__(16) unsigned char lds[BM * BK * 2 + BN * BK * 2];

    const int tid  = threadIdx.x;
    const int n0   = blockIdx.x * BN;
    const int m0   = blockIdx.y * BM;
    const int wave = tid >> 6;
    const int lane = tid & 63;
    const int wm   = (wave >> 1) * 64;
    const int wn   = (wave & 1) * 64;
    const int l15  = lane & 15;
    const int lhi  = lane >> 4;

    // staging maps
    const int arow  = tid >> 4;          // 0..15 (A row within 16-row stripe)
    const int acol4 = (tid & 15) << 2;   // 0..60 (A col, float4 granular)
    const int bnl   = tid & 127;         // 0..127 (B n within tile)
    const int brb   = tid >> 7;          // 0..1   (B qweight-row phase)
    const int col   = n0 + bnl;          // global n for this staging thread

    f32x4 acc[4][4] = {};

    for (int kt = 0; kt < K_DIM / BK; ++kt) {
        const int k0 = kt * BK;

        // ---- stage A: f32 -> bf16, swizzled ----
        #pragma unroll
        for (int r8 = 0; r8 < 8; ++r8) {
            const int row = (r8 << 4) + arow;
            f32x4 v = *reinterpret_cast<const f32x4*>(
                X + (size_t)(m0 + row) * K_DIM + (k0 + acol4));
            u16x4 h;
            #pragma unroll
            for (int e = 0; e < 4; ++e) h[e] = f2bf(v[e]);
            const int boff = row * (BK * 2) + ((acol4 << 1) ^ ((row & 7) << 4));
            *reinterpret_cast<u16x4*>(lds + boff) = h;
        }

        // ---- stage B: int4 dequant -> bf16, K-contiguous per n, swizzled ----
        {
            const int g    = k0 >> 7;      // BK=64 tile sits inside one group of 128
            const int zp   = (((unsigned)QZ[g * (N_DIM / 8) + (col >> 3)])
                              >> ((col & 7) << 2)) & 15;
            const float sc = SC[g * N_DIM + col];
            const float zs = (float)zp * sc;
            #pragma unroll
            for (int rb = 0; rb < 4; ++rb) {
                const int rl = (rb << 1) + brb;                 // 0..7
                const unsigned qw =
                    (unsigned)QW[(size_t)((k0 >> 3) + rl) * N_DIM + col];
                u16x8 h;
                #pragma unroll
                for (int j = 0; j < 8; ++j) {
                    float w = (float)((qw >> (j << 2)) & 15u) * sc - zs;
                    h[j] = f2bf(w);
                }
                const int boff = BM * BK * 2 + bnl * (BK * 2)
                               + ((rl << 4) ^ ((bnl & 7) << 4));
                *reinterpret_cast<u16x8*>(lds + boff) = h;
            }
        }

        __syncthreads();

        // ---- compute: 2 k-steps x 16 MFMA ----
        #pragma unroll
        for (int kk = 0; kk < 2; ++kk) {
            bf16x8 afr[4], bfr[4];
            #pragma unroll
            for (int i = 0; i < 4; ++i) {
                const int row  = wm + (i << 4) + l15;
                const int boff = row * (BK * 2)
                               + (((kk << 6) + (lhi << 4)) ^ ((row & 7) << 4));
                afr[i] = *reinterpret_cast<const bf16x8*>(lds + boff);
            }
            #pragma unroll
            for (int j = 0; j < 4; ++j) {
                const int n    = wn + (j << 4) + l15;
                const int boff = BM * BK * 2 + n * (BK * 2)
                               + (((kk << 6) + (lhi << 4)) ^ ((n & 7) << 4));
                bfr[j] = *reinterpret_cast<const bf16x8*>(lds + boff);
            }
            #pragma unroll
            for (int i = 0; i < 4; ++i)
                #pragma unroll
                for (int j = 0; j < 4; ++j)
                    acc[i][j] = __builtin_amdgcn_mfma_f32_16x16x32_bf16(
                        afr[i], bfr[j], acc[i][j], 0, 0, 0);
        }

        __syncthreads();
    }

    // ---- epilogue: C = acc + bias ----
    #pragma unroll
    for (int j = 0; j < 4; ++j) {
        const int n    = n0 + wn + (j << 4) + l15;
        const float bv = BIAS[n];
        #pragma unroll
        for (int i = 0; i < 4; ++i) {
            const int mb = m0 + wm + (i << 4) + (lhi << 2);
            #pragma unroll
            for (int t = 0; t < 4; ++t)
                OUT[(size_t)(mb + t) * N_DIM + n] = acc[i][j][t] + bv;
        }
    }
}

extern "C" void kernel_launch(void* const* d_in, const int* in_sizes, int n_in,
                              void* d_out, int out_size, void* d_ws, size_t ws_size,
                              hipStream_t stream) {
    const float* X  = (const float*)d_in[0];
    const int*   QW = (const int*)d_in[1];
    const int*   QZ = (const int*)d_in[2];
    const float* SC = (const float*)d_in[3];
    const float* BI = (const float*)d_in[4];
    float*      OUT = (float*)d_out;

    dim3 grid(N_DIM / BN, M_DIM / BM);  // 86 x 32, all tiles exact
    gptq_gemm_kernel<<<grid, 256, 0, stream>>>(X, QW, QZ, SC, BI, OUT);
}

// Round 2
// 616.031 us; speedup vs baseline: 1.1305x; 1.1305x over previous
//
#include <hip/hip_runtime.h>
#include <hip/hip_bf16.h>
#include <stdint.h>

#define M_DIM 4096
#define N_DIM 11008
#define K_DIM 4096
#define BM 128
#define BN 128
#define BK 64

typedef float f32x4 __attribute__((ext_vector_type(4)));
typedef __bf16 bf16x8 __attribute__((ext_vector_type(8)));
typedef unsigned short u16x8 __attribute__((ext_vector_type(8)));
typedef unsigned short u16x4 __attribute__((ext_vector_type(4)));

typedef __attribute__((address_space(1))) const unsigned int guint;
typedef __attribute__((address_space(3))) unsigned int luint;
#define GLOAD_LDS16(g, l) \
    __builtin_amdgcn_global_load_lds((guint*)(g), (luint*)(l), 16, 0, 0)

__device__ __forceinline__ unsigned short f2bf(float f) {
    union { float f; unsigned u; } v; v.f = f;
    return (unsigned short)((v.u + 0x7FFFu + ((v.u >> 16) & 1u)) >> 16);
}

// ---------------- Pass 1a: X f32 -> bf16 ----------------
__global__ void __launch_bounds__(256) cvt_x_kernel(
    const float* __restrict__ X, __hip_bfloat16* __restrict__ Y)
{
    const size_t i = ((size_t)blockIdx.x * 256 + threadIdx.x) * 8;
    f32x4 a = *reinterpret_cast<const f32x4*>(X + i);
    f32x4 b = *reinterpret_cast<const f32x4*>(X + i + 4);
    bf16x8 h;
    #pragma unroll
    for (int e = 0; e < 4; ++e) { h[e] = (__bf16)a[e]; h[e + 4] = (__bf16)b[e]; }
    *reinterpret_cast<bf16x8*>(Y + i) = h;
}

// ---------------- Pass 1b: GPTQ int4 -> Wt[n][k] bf16 ----------------
__global__ void __launch_bounds__(256) dequant_kernel(
    const int* __restrict__ QW, const int* __restrict__ QZ,
    const float* __restrict__ SC, __hip_bfloat16* __restrict__ Wt)
{
    const int n   = blockIdx.x * 64 + (threadIdx.x & 63);
    const int k64 = blockIdx.y * 4 + (threadIdx.x >> 6);   // 64 k-values per thread
    const int g   = k64 >> 1;                              // group = k/128
    const int zp  = ((unsigned)QZ[g * (N_DIM / 8) + (n >> 3)] >> ((n & 7) << 2)) & 15;
    const float sc = SC[g * N_DIM + n];
    const float zs = (float)zp * sc;
    #pragma unroll
    for (int r = 0; r < 8; ++r) {
        const unsigned qw = (unsigned)QW[(size_t)(k64 * 8 + r) * N_DIM + n];
        bf16x8 h;
        #pragma unroll
        for (int j = 0; j < 8; ++j)
            h[j] = (__bf16)((float)((qw >> (j * 4)) & 15u) * sc - zs);
        *reinterpret_cast<bf16x8*>(Wt + (size_t)n * K_DIM + k64 * 64 + r * 8) = h;
    }
}

// ---------------- Pass 2: bf16 GEMM (m97 structure) ----------------
__global__ void __launch_bounds__(256) gemm_bf16_kernel(
    const __hip_bfloat16* __restrict__ A,   // [4096][4096] row-major (m,k)
    const __hip_bfloat16* __restrict__ Bt,  // [11008][4096] row-major (n,k)
    const float* __restrict__ BIAS, float* __restrict__ OUT)
{
    __shared__ __align__(16) unsigned char lds[BM * BK * 2 + BN * BK * 2];

    const int tid  = threadIdx.x;
    const int n0   = blockIdx.x * BN;
    const int m0   = blockIdx.y * BM;
    const int wave = tid >> 6;
    const int lane = tid & 63;
    const int wm   = (wave >> 1) * 64;
    const int wn   = (wave & 1) * 64;
    const int l15  = lane & 15;
    const int lhi  = lane >> 4;

    // per-lane source geometry for global_load_lds (byte b = wave*4096 + i*1024 + lane*16)
    f32x4 acc[4][4] = {};

    for (int kt = 0; kt < K_DIM / BK; ++kt) {
        const int k0 = kt * BK;
        #pragma unroll
        for (int i = 0; i < 4; ++i) {
            const int b   = wave * 4096 + i * 1024 + lane * 16;
            const int row = b >> 7;          // 0..127
            const int ke  = (b & 127) >> 1;  // element offset in k (0..56, x8 aligned)
            GLOAD_LDS16(A  + (size_t)(m0 + row) * K_DIM + k0 + ke,
                        lds + wave * 4096 + i * 1024);
            GLOAD_LDS16(Bt + (size_t)(n0 + row) * K_DIM + k0 + ke,
                        lds + 16384 + wave * 4096 + i * 1024);
        }
        __syncthreads();

        #pragma unroll
        for (int kk = 0; kk < 2; ++kk) {
            bf16x8 afr[4], bfr[4];
            #pragma unroll
            for (int i = 0; i < 4; ++i) {
                const int row = wm + (i << 4) + l15;
                afr[i] = *reinterpret_cast<const bf16x8*>(
                    lds + row * 128 + (kk << 6) + (lhi << 4));
            }
            #pragma unroll
            for (int j = 0; j < 4; ++j) {
                const int n = wn + (j << 4) + l15;
                bfr[j] = *reinterpret_cast<const bf16x8*>(
                    lds + 16384 + n * 128 + (kk << 6) + (lhi << 4));
            }
            #pragma unroll
            for (int i = 0; i < 4; ++i)
                #pragma unroll
                for (int j = 0; j < 4; ++j)
                    acc[i][j] = __builtin_amdgcn_mfma_f32_16x16x32_bf16(
                        afr[i], bfr[j], acc[i][j], 0, 0, 0);
        }
        __syncthreads();
    }

    #pragma unroll
    for (int j = 0; j < 4; ++j) {
        const int n    = n0 + wn + (j << 4) + l15;
        const float bv = BIAS[n];
        #pragma unroll
        for (int i = 0; i < 4; ++i) {
            const int mb = m0 + wm + (i << 4) + (lhi << 2);
            #pragma unroll
            for (int t = 0; t < 4; ++t)
                OUT[(size_t)(mb + t) * N_DIM + n] = acc[i][j][t] + bv;
        }
    }
}

// ---------------- Fallback: round-1 fused kernel ----------------
__global__ void __launch_bounds__(256) gptq_gemm_kernel(
    const float* __restrict__ X, const int* __restrict__ QW,
    const int* __restrict__ QZ, const float* __restrict__ SC,
    const float* __restrict__ BIAS, float* __restrict__ OUT)
{
    __shared__ __align__(16) unsigned char lds[BM * BK * 2 + BN * BK * 2];
    const int tid  = threadIdx.x;
    const int n0   = blockIdx.x * BN;
    const int m0   = blockIdx.y * BM;
    const int wave = tid >> 6;
    const int lane = tid & 63;
    const int wm   = (wave >> 1) * 64;
    const int wn   = (wave & 1) * 64;
    const int l15  = lane & 15;
    const int lhi  = lane >> 4;
    const int arow  = tid >> 4;
    const int acol4 = (tid & 15) << 2;
    const int bnl   = tid & 127;
    const int brb   = tid >> 7;
    const int col   = n0 + bnl;

    f32x4 acc[4][4] = {};
    for (int kt = 0; kt < K_DIM / BK; ++kt) {
        const int k0 = kt * BK;
        #pragma unroll
        for (int r8 = 0; r8 < 8; ++r8) {
            const int row = (r8 << 4) + arow;
            f32x4 v = *reinterpret_cast<const f32x4*>(
                X + (size_t)(m0 + row) * K_DIM + (k0 + acol4));
            u16x4 h;
            #pragma unroll
            for (int e = 0; e < 4; ++e) h[e] = f2bf(v[e]);
            const int boff = row * (BK * 2) + ((acol4 << 1) ^ ((row & 7) << 4));
            *reinterpret_cast<u16x4*>(lds + boff) = h;
        }
        {
            const int g    = k0 >> 7;
            const int zp   = (((unsigned)QZ[g * (N_DIM / 8) + (col >> 3)])
                              >> ((col & 7) << 2)) & 15;
            const float sc = SC[g * N_DIM + col];
            const float zs = (float)zp * sc;
            #pragma unroll
            for (int rb = 0; rb < 4; ++rb) {
                const int rl = (rb << 1) + brb;
                const unsigned qw =
                    (unsigned)QW[(size_t)((k0 >> 3) + rl) * N_DIM + col];
                u16x8 h;
                #pragma unroll
                for (int j = 0; j < 8; ++j) {
                    float w = (float)((qw >> (j << 2)) & 15u) * sc - zs;
                    h[j] = f2bf(w);
                }
                const int boff = BM * BK * 2 + bnl * (BK * 2)
                               + ((rl << 4) ^ ((bnl & 7) << 4));
                *reinterpret_cast<u16x8*>(lds + boff) = h;
            }
        }
        __syncthreads();
        #pragma unroll
        for (int kk = 0; kk < 2; ++kk) {
            bf16x8 afr[4], bfr[4];
            #pragma unroll
            for (int i = 0; i < 4; ++i) {
                const int row  = wm + (i << 4) + l15;
                afr[i] = *reinterpret_cast<const bf16x8*>(
                    lds + row * 128 + (((kk << 6) + (lhi << 4)) ^ ((row & 7) << 4)));
            }
            #pragma unroll
            for (int j = 0; j < 4; ++j) {
                const int n = wn + (j << 4) + l15;
                bfr[j] = *reinterpret_cast<const bf16x8*>(
                    lds + 16384 + n * 128 + (((kk << 6) + (lhi << 4)) ^ ((n & 7) << 4)));
            }
            #pragma unroll
            for (int i = 0; i < 4; ++i)
                #pragma unroll
                for (int j = 0; j < 4; ++j)
                    acc[i][j] = __builtin_amdgcn_mfma_f32_16x16x32_bf16(
                        afr[i], bfr[j], acc[i][j], 0, 0, 0);
        }
        __syncthreads();
    }
    #pragma unroll
    for (int j = 0; j < 4; ++j) {
        const int n    = n0 + wn + (j << 4) + l15;
        const float bv = BIAS[n];
        #pragma unroll
        for (int i = 0; i < 4; ++i) {
            const int mb = m0 + wm + (i << 4) + (lhi << 2);
            #pragma unroll
            for (int t = 0; t < 4; ++t)
                OUT[(size_t)(mb + t) * N_DIM + n] = acc[i][j][t] + bv;
        }
    }
}

extern "C" void kernel_launch(void* const* d_in, const int* in_sizes, int n_in,
                              void* d_out, int out_size, void* d_ws, size_t ws_size,
                              hipStream_t stream) {
    const float* X  = (const float*)d_in[0];
    const int*   QW = (const int*)d_in[1];
    const int*   QZ = (const int*)d_in[2];
    const float* SC = (const float*)d_in[3];
    const float* BI = (const float*)d_in[4];
    float*      OUT = (float*)d_out;

    const size_t xbf_bytes = (size_t)M_DIM * K_DIM * 2;          // 33,554,432
    const size_t wt_bytes  = (size_t)N_DIM * K_DIM * 2;          // 90,177,536

    if (ws_size >= xbf_bytes + wt_bytes) {
        __hip_bfloat16* Xbf = (__hip_bfloat16*)d_ws;
        __hip_bfloat16* Wt  = (__hip_bfloat16*)((char*)d_ws + xbf_bytes);

        cvt_x_kernel<<<(M_DIM * K_DIM) / (256 * 8), 256, 0, stream>>>(X, Xbf);
        dequant_kernel<<<dim3(N_DIM / 64, K_DIM / 256), 256, 0, stream>>>(QW, QZ, SC, Wt);
        gemm_bf16_kernel<<<dim3(N_DIM / BN, M_DIM / BM), 256, 0, stream>>>(Xbf, Wt, BI, OUT);
    } else {
        gptq_gemm_kernel<<<dim3(N_DIM / BN, M_DIM / BM), 256, 0, stream>>>(X, QW, QZ, SC, BI, OUT);
    }
}

// Round 3
// 422.066 us; speedup vs baseline: 1.6500x; 1.4596x over previous
//
#include <hip/hip_runtime.h>
#include <hip/hip_bf16.h>
#include <stdint.h>

#define M_DIM 4096
#define N_DIM 11008
#define K_DIM 4096

typedef float f32x4 __attribute__((ext_vector_type(4)));
typedef __bf16 bf16x8 __attribute__((ext_vector_type(8)));
typedef unsigned short u16x8 __attribute__((ext_vector_type(8)));
typedef unsigned short u16x4 __attribute__((ext_vector_type(4)));

typedef __attribute__((address_space(1))) const unsigned int guint;
typedef __attribute__((address_space(3))) unsigned int luint;
#define GLOAD_LDS16(g, l) \
    __builtin_amdgcn_global_load_lds((guint*)(g), (luint*)(l), 16, 0, 0)

#define WAIT_VM8() asm volatile("s_waitcnt vmcnt(8)" ::: "memory")
#define WAIT_VM4() asm volatile("s_waitcnt vmcnt(4)" ::: "memory")
#define WAIT_VM0() asm volatile("s_waitcnt vmcnt(0)" ::: "memory")

__device__ __forceinline__ unsigned short f2bf(float f) {
    union { float f; unsigned u; } v; v.f = f;
    return (unsigned short)((v.u + 0x7FFFu + ((v.u >> 16) & 1u)) >> 16);
}

// ---------------- Pass 1a: X f32 -> bf16 ----------------
__global__ void __launch_bounds__(256) cvt_x_kernel(
    const float* __restrict__ X, __hip_bfloat16* __restrict__ Y)
{
    const size_t i = ((size_t)blockIdx.x * 256 + threadIdx.x) * 8;
    f32x4 a = *reinterpret_cast<const f32x4*>(X + i);
    f32x4 b = *reinterpret_cast<const f32x4*>(X + i + 4);
    bf16x8 h;
    #pragma unroll
    for (int e = 0; e < 4; ++e) { h[e] = (__bf16)a[e]; h[e + 4] = (__bf16)b[e]; }
    *reinterpret_cast<bf16x8*>(Y + i) = h;
}

// ---------------- Pass 1b: GPTQ int4 -> Wt[n][k] bf16 ----------------
__global__ void __launch_bounds__(256) dequant_kernel(
    const int* __restrict__ QW, const int* __restrict__ QZ,
    const float* __restrict__ SC, __hip_bfloat16* __restrict__ Wt)
{
    const int n   = blockIdx.x * 64 + (threadIdx.x & 63);
    const int k64 = blockIdx.y * 4 + (threadIdx.x >> 6);   // 64 k-values per thread
    const int g   = k64 >> 1;                              // group = k/128
    const int zp  = ((unsigned)QZ[g * (N_DIM / 8) + (n >> 3)] >> ((n & 7) << 2)) & 15;
    const float sc = SC[g * N_DIM + n];
    const float zs = (float)zp * sc;
    #pragma unroll
    for (int r = 0; r < 8; ++r) {
        const unsigned qw = (unsigned)QW[(size_t)(k64 * 8 + r) * N_DIM + n];
        bf16x8 h;
        #pragma unroll
        for (int j = 0; j < 8; ++j)
            h[j] = (__bf16)((float)((qw >> (j * 4)) & 15u) * sc - zs);
        *reinterpret_cast<bf16x8*>(Wt + (size_t)n * K_DIM + k64 * 64 + r * 8) = h;
    }
}

// ---------------- Pass 2: 256x256 deep-pipelined bf16 GEMM ----------------
// BK=32, 4-buffer LDS ring (4 x 32KB), counted vmcnt(8), 1 barrier/K-tile,
// XOR slot-swizzle (slot ^= (row>>1)&3) staged via pre-swizzled global source.
__global__ void __launch_bounds__(512, 2) gemm_bf16_kernel(
    const __hip_bfloat16* __restrict__ A,   // [4096][4096] (m,k)
    const __hip_bfloat16* __restrict__ Bt,  // [11008][4096] (n,k)
    const float* __restrict__ BIAS, float* __restrict__ OUT)
{
    extern __shared__ unsigned char lds[];  // 131072 bytes: buf d at d*32768; A +0, B +16384

    const int tid  = threadIdx.x;
    const int wave = tid >> 6;
    const int lane = tid & 63;
    const int l15  = lane & 15;
    const int lhi  = lane >> 4;
    const int wr   = wave >> 2;   // 0..1  (M)
    const int wc   = wave & 3;    // 0..3  (N)

    // XCD-bijective swizzle: 688 blocks = 8 XCDs x 86, M-fastest within chunk
    const int bid = blockIdx.x;
    const int swz = (bid & 7) * 86 + (bid >> 3);
    const int m0  = (swz & 15) * 256;
    const int n0  = (swz >> 4) * 256;

    // ---- staging geometry (per-lane global src, linear wave-uniform LDS dest) ----
    // dest byte (within 16KB op-tile) = q*8192 + wave*1024 + lane*16
    //   row = q*128 + wave*16 + (lane>>2), slot sd = lane&3
    //   src k-elems = (sd ^ ((row>>1)&3))*8  ->  kswz lane-local
    const int r_loc  = wave * 16 + (lane >> 2);
    const int kswz8  = ((lane & 3) ^ ((lane >> 3) & 3)) * 8;
    const __hip_bfloat16* Asrc = A  + (size_t)(m0 + r_loc) * K_DIM + kswz8;
    const __hip_bfloat16* Bsrc = Bt + (size_t)(n0 + r_loc) * K_DIM + kswz8;
    const int ldst = wave * 1024;

    // ---- fragment-read byte offsets (constant per thread; add bufbase) ----
    const int slotx = ((lhi ^ ((l15 >> 1) & 3)) << 4);
    int aoff[8], boff[4];
    #pragma unroll
    for (int i = 0; i < 8; ++i)
        aoff[i] = (wr * 128 + i * 16 + l15) * 64 + slotx;
    #pragma unroll
    for (int j = 0; j < 4; ++j)
        boff[j] = 16384 + (wc * 64 + j * 16 + l15) * 64 + slotx;

    f32x4 acc[8][4] = {};

    auto stage = [&](int c) {
        const int buf = (c & 3) * 32768;
        const size_t kof = (size_t)c * 32;
        GLOAD_LDS16(Asrc + kof,                        lds + buf + ldst);
        GLOAD_LDS16(Asrc + kof + (size_t)128 * K_DIM,  lds + buf + 8192 + ldst);
        GLOAD_LDS16(Bsrc + kof,                        lds + buf + 16384 + ldst);
        GLOAD_LDS16(Bsrc + kof + (size_t)128 * K_DIM,  lds + buf + 16384 + 8192 + ldst);
    };

    auto compute = [&](int buf) {
        bf16x8 bfr[4], afr[4];
        #pragma unroll
        for (int j = 0; j < 4; ++j)
            bfr[j] = *reinterpret_cast<const bf16x8*>(lds + buf + boff[j]);
        #pragma unroll
        for (int i = 0; i < 4; ++i)
            afr[i] = *reinterpret_cast<const bf16x8*>(lds + buf + aoff[i]);
        __builtin_amdgcn_s_setprio(1);
        #pragma unroll
        for (int i = 0; i < 4; ++i)
            #pragma unroll
            for (int j = 0; j < 4; ++j)
                acc[i][j] = __builtin_amdgcn_mfma_f32_16x16x32_bf16(
                    afr[i], bfr[j], acc[i][j], 0, 0, 0);
        __builtin_amdgcn_s_setprio(0);
        #pragma unroll
        for (int i = 0; i < 4; ++i)
            afr[i] = *reinterpret_cast<const bf16x8*>(lds + buf + aoff[i + 4]);
        __builtin_amdgcn_s_setprio(1);
        #pragma unroll
        for (int i = 0; i < 4; ++i)
            #pragma unroll
            for (int j = 0; j < 4; ++j)
                acc[i + 4][j] = __builtin_amdgcn_mfma_f32_16x16x32_bf16(
                    afr[i], bfr[j], acc[i + 4][j], 0, 0, 0);
        __builtin_amdgcn_s_setprio(0);
    };

    // prologue: fill 3 tiles of the ring
    stage(0); stage(1); stage(2);

    for (int c = 0; c < 125; ++c) {
        WAIT_VM8();
        __builtin_amdgcn_s_barrier();
        __builtin_amdgcn_sched_barrier(0);
        stage(c + 3);
        compute((c & 3) * 32768);
    }
    WAIT_VM8();
    __builtin_amdgcn_s_barrier();
    __builtin_amdgcn_sched_barrier(0);
    compute((125 & 3) * 32768);
    WAIT_VM4();
    __builtin_amdgcn_s_barrier();
    __builtin_amdgcn_sched_barrier(0);
    compute((126 & 3) * 32768);
    WAIT_VM0();
    __builtin_amdgcn_s_barrier();
    __builtin_amdgcn_sched_barrier(0);
    compute((127 & 3) * 32768);

    // ---- epilogue: OUT = acc + bias ----
    #pragma unroll
    for (int j = 0; j < 4; ++j) {
        const int n    = n0 + wc * 64 + j * 16 + l15;
        const float bv = BIAS[n];
        #pragma unroll
        for (int i = 0; i < 8; ++i) {
            const int mb = m0 + wr * 128 + i * 16 + (lhi << 2);
            #pragma unroll
            for (int t = 0; t < 4; ++t)
                OUT[(size_t)(mb + t) * N_DIM + n] = acc[i][j][t] + bv;
        }
    }
}

// ---------------- Fallback: round-1 fused kernel ----------------
__global__ void __launch_bounds__(256) gptq_gemm_kernel(
    const float* __restrict__ X, const int* __restrict__ QW,
    const int* __restrict__ QZ, const float* __restrict__ SC,
    const float* __restrict__ BIAS, float* __restrict__ OUT)
{
    __shared__ __align__(16) unsigned char slds[32768];
    const int tid  = threadIdx.x;
    const int n0   = blockIdx.x * 128;
    const int m0   = blockIdx.y * 128;
    const int wave = tid >> 6;
    const int lane = tid & 63;
    const int wm   = (wave >> 1) * 64;
    const int wn   = (wave & 1) * 64;
    const int l15  = lane & 15;
    const int lhi  = lane >> 4;
    const int arow  = tid >> 4;
    const int acol4 = (tid & 15) << 2;
    const int bnl   = tid & 127;
    const int brb   = tid >> 7;
    const int col   = n0 + bnl;

    f32x4 acc[4][4] = {};
    for (int kt = 0; kt < K_DIM / 64; ++kt) {
        const int k0 = kt * 64;
        #pragma unroll
        for (int r8 = 0; r8 < 8; ++r8) {
            const int row = (r8 << 4) + arow;
            f32x4 v = *reinterpret_cast<const f32x4*>(
                X + (size_t)(m0 + row) * K_DIM + (k0 + acol4));
            u16x4 h;
            #pragma unroll
            for (int e = 0; e < 4; ++e) h[e] = f2bf(v[e]);
            const int bo = row * 128 + ((acol4 << 1) ^ ((row & 7) << 4));
            *reinterpret_cast<u16x4*>(slds + bo) = h;
        }
        {
            const int g    = k0 >> 7;
            const int zp   = (((unsigned)QZ[g * (N_DIM / 8) + (col >> 3)])
                              >> ((col & 7) << 2)) & 15;
            const float sc = SC[g * N_DIM + col];
            const float zs = (float)zp * sc;
            #pragma unroll
            for (int rb = 0; rb < 4; ++rb) {
                const int rl = (rb << 1) + brb;
                const unsigned qw =
                    (unsigned)QW[(size_t)((k0 >> 3) + rl) * N_DIM + col];
                u16x8 h;
                #pragma unroll
                for (int j = 0; j < 8; ++j) {
                    float w = (float)((qw >> (j << 2)) & 15u) * sc - zs;
                    h[j] = f2bf(w);
                }
                const int bo = 16384 + bnl * 128 + ((rl << 4) ^ ((bnl & 7) << 4));
                *reinterpret_cast<u16x8*>(slds + bo) = h;
            }
        }
        __syncthreads();
        #pragma unroll
        for (int kk = 0; kk < 2; ++kk) {
            bf16x8 afr[4], bfr[4];
            #pragma unroll
            for (int i = 0; i < 4; ++i) {
                const int row = wm + (i << 4) + l15;
                afr[i] = *reinterpret_cast<const bf16x8*>(
                    slds + row * 128 + (((kk << 6) + (lhi << 4)) ^ ((row & 7) << 4)));
            }
            #pragma unroll
            for (int j = 0; j < 4; ++j) {
                const int n = wn + (j << 4) + l15;
                bfr[j] = *reinterpret_cast<const bf16x8*>(
                    slds + 16384 + n * 128 + (((kk << 6) + (lhi << 4)) ^ ((n & 7) << 4)));
            }
            #pragma unroll
            for (int i = 0; i < 4; ++i)
                #pragma unroll
                for (int j = 0; j < 4; ++j)
                    acc[i][j] = __builtin_amdgcn_mfma_f32_16x16x32_bf16(
                        afr[i], bfr[j], acc[i][j], 0, 0, 0);
        }
        __syncthreads();
    }
    #pragma unroll
    for (int j = 0; j < 4; ++j) {
        const int n    = n0 + wn + (j << 4) + l15;
        const float bv = BIAS[n];
        #pragma unroll
        for (int i = 0; i < 4; ++i) {
            const int mb = m0 + wm + (i << 4) + (lhi << 2);
            #pragma unroll
            for (int t = 0; t < 4; ++t)
                OUT[(size_t)(mb + t) * N_DIM + n] = acc[i][j][t] + bv;
        }
    }
}

extern "C" void kernel_launch(void* const* d_in, const int* in_sizes, int n_in,
                              void* d_out, int out_size, void* d_ws, size_t ws_size,
                              hipStream_t stream) {
    const float* X  = (const float*)d_in[0];
    const int*   QW = (const int*)d_in[1];
    const int*   QZ = (const int*)d_in[2];
    const float* SC = (const float*)d_in[3];
    const float* BI = (const float*)d_in[4];
    float*      OUT = (float*)d_out;

    const size_t xbf_bytes = (size_t)M_DIM * K_DIM * 2;
    const size_t wt_bytes  = (size_t)N_DIM * K_DIM * 2;

    if (ws_size >= xbf_bytes + wt_bytes) {
        __hip_bfloat16* Xbf = (__hip_bfloat16*)d_ws;
        __hip_bfloat16* Wt  = (__hip_bfloat16*)((char*)d_ws + xbf_bytes);

        cvt_x_kernel<<<(M_DIM * K_DIM) / (256 * 8), 256, 0, stream>>>(X, Xbf);
        dequant_kernel<<<dim3(N_DIM / 64, K_DIM / 256), 256, 0, stream>>>(QW, QZ, SC, Wt);
        gemm_bf16_kernel<<<dim3((M_DIM / 256) * (N_DIM / 256)), 512, 131072, stream>>>(
            Xbf, Wt, BI, OUT);
    } else {
        gptq_gemm_kernel<<<dim3(N_DIM / 128, M_DIM / 128), 256, 0, stream>>>(
            X, QW, QZ, SC, BI, OUT);
    }
}

// Round 4
// 406.310 us; speedup vs baseline: 1.7140x; 1.0388x over previous
//
#include <hip/hip_runtime.h>
#include <hip/hip_bf16.h>
#include <stdint.h>

#define M_DIM 4096
#define N_DIM 11008
#define K_DIM 4096

typedef float f32x4 __attribute__((ext_vector_type(4)));
typedef __bf16 bf16x8 __attribute__((ext_vector_type(8)));
typedef unsigned short u16x8 __attribute__((ext_vector_type(8)));
typedef unsigned short u16x4 __attribute__((ext_vector_type(4)));

typedef __attribute__((address_space(1))) const unsigned int guint;
typedef __attribute__((address_space(3))) unsigned int luint;
#define GLOAD_LDS16(g, l) \
    __builtin_amdgcn_global_load_lds((guint*)(g), (luint*)(l), 16, 0, 0)

#define WAIT_VM4() asm volatile("s_waitcnt vmcnt(4)" ::: "memory")
#define WAIT_VM2() asm volatile("s_waitcnt vmcnt(2)" ::: "memory")
#define WAIT_VM0() asm volatile("s_waitcnt vmcnt(0)" ::: "memory")

__device__ __forceinline__ unsigned short f2bf(float f) {
    union { float f; unsigned u; } v; v.f = f;
    return (unsigned short)((v.u + 0x7FFFu + ((v.u >> 16) & 1u)) >> 16);
}

// ---------------- Pass 1a: X f32 -> bf16 ----------------
__global__ void __launch_bounds__(256) cvt_x_kernel(
    const float* __restrict__ X, __hip_bfloat16* __restrict__ Y)
{
    const size_t i = ((size_t)blockIdx.x * 256 + threadIdx.x) * 8;
    f32x4 a = *reinterpret_cast<const f32x4*>(X + i);
    f32x4 b = *reinterpret_cast<const f32x4*>(X + i + 4);
    bf16x8 h;
    #pragma unroll
    for (int e = 0; e < 4; ++e) { h[e] = (__bf16)a[e]; h[e + 4] = (__bf16)b[e]; }
    *reinterpret_cast<bf16x8*>(Y + i) = h;
}

// ---------------- Pass 1b: GPTQ int4 -> Wt[n][k] bf16 ----------------
__global__ void __launch_bounds__(256) dequant_kernel(
    const int* __restrict__ QW, const int* __restrict__ QZ,
    const float* __restrict__ SC, __hip_bfloat16* __restrict__ Wt)
{
    const int n   = blockIdx.x * 64 + (threadIdx.x & 63);
    const int k64 = blockIdx.y * 4 + (threadIdx.x >> 6);
    const int g   = k64 >> 1;
    const int zp  = ((unsigned)QZ[g * (N_DIM / 8) + (n >> 3)] >> ((n & 7) << 2)) & 15;
    const float sc = SC[g * N_DIM + n];
    const float zs = (float)zp * sc;
    #pragma unroll
    for (int r = 0; r < 8; ++r) {
        const unsigned qw = (unsigned)QW[(size_t)(k64 * 8 + r) * N_DIM + n];
        bf16x8 h;
        #pragma unroll
        for (int j = 0; j < 8; ++j)
            h[j] = (__bf16)((float)((qw >> (j * 4)) & 15u) * sc - zs);
        *reinterpret_cast<bf16x8*>(Wt + (size_t)n * K_DIM + k64 * 64 + r * 8) = h;
    }
}

// ---------------- Pass 2: 256x256 deep-pipelined bf16 GEMM ----------------
// 1024 threads (16 waves, 4x4), BK=32, 4-buffer LDS ring (4 x 32KB),
// counted vmcnt(4), 1 barrier/K-tile, XOR slot-swizzle via pre-swizzled
// global source (linear gload_lds dest).  4 waves/SIMD occupancy.
__global__ void __launch_bounds__(1024, 4) gemm_bf16_kernel(
    const __hip_bfloat16* __restrict__ A,   // [4096][4096] (m,k)
    const __hip_bfloat16* __restrict__ Bt,  // [11008][4096] (n,k)
    const float* __restrict__ BIAS, float* __restrict__ OUT)
{
    extern __shared__ unsigned char lds[];  // 131072: buf d at d*32768; A +0, B +16384

    const int tid  = threadIdx.x;
    const int wave = tid >> 6;
    const int lane = tid & 63;
    const int l15  = lane & 15;
    const int lhi  = lane >> 4;
    const int wr   = wave >> 2;   // 0..3 (M, 64-row strips)
    const int wc   = wave & 3;    // 0..3 (N, 64-col strips)

    // XCD-bijective swizzle: 688 blocks = 8 XCDs x 86, M-fastest within chunk
    const int bid = blockIdx.x;
    const int swz = (bid & 7) * 86 + (bid >> 3);
    const int m0  = (swz & 15) * 256;
    const int n0  = (swz >> 4) * 256;

    // staging: thread t writes dest byte t*16 in a 16KB op-tile.
    // row = t>>2 (0..255), slot = t&3; source k pre-swizzled: slot ^ ((row>>1)&3)
    const int r_loc = wave * 16 + (lane >> 2);
    const int kswz8 = ((lane & 3) ^ ((lane >> 3) & 3)) * 8;
    const __hip_bfloat16* Asrc = A  + (size_t)(m0 + r_loc) * K_DIM + kswz8;
    const __hip_bfloat16* Bsrc = Bt + (size_t)(n0 + r_loc) * K_DIM + kswz8;
    const int ldst = wave * 1024;  // 64 lanes * 16B

    // fragment-read offsets (constant per thread; add buf base)
    const int slotx = ((lhi ^ ((l15 >> 1) & 3)) << 4);
    int aoff[4], boff[4];
    #pragma unroll
    for (int i = 0; i < 4; ++i)
        aoff[i] = (wr * 64 + i * 16 + l15) * 64 + slotx;
    #pragma unroll
    for (int j = 0; j < 4; ++j)
        boff[j] = 16384 + (wc * 64 + j * 16 + l15) * 64 + slotx;

    f32x4 acc[4][4] = {};

    auto stage = [&](int c) {
        const int buf = (c & 3) * 32768;
        const size_t kof = (size_t)c * 32;
        GLOAD_LDS16(Asrc + kof, lds + buf + ldst);
        GLOAD_LDS16(Bsrc + kof, lds + buf + 16384 + ldst);
    };

    auto compute = [&](int buf) {
        bf16x8 afr[4], bfr[4];
        #pragma unroll
        for (int j = 0; j < 4; ++j)
            bfr[j] = *reinterpret_cast<const bf16x8*>(lds + buf + boff[j]);
        #pragma unroll
        for (int i = 0; i < 4; ++i)
            afr[i] = *reinterpret_cast<const bf16x8*>(lds + buf + aoff[i]);
        __builtin_amdgcn_s_setprio(1);
        #pragma unroll
        for (int i = 0; i < 4; ++i)
            #pragma unroll
            for (int j = 0; j < 4; ++j)
                acc[i][j] = __builtin_amdgcn_mfma_f32_16x16x32_bf16(
                    afr[i], bfr[j], acc[i][j], 0, 0, 0);
        __builtin_amdgcn_s_setprio(0);
    };

    // prologue: fill 3 ring slots
    stage(0); stage(1); stage(2);

    for (int c = 0; c < 125; ++c) {
        WAIT_VM4();
        __builtin_amdgcn_s_barrier();
        __builtin_amdgcn_sched_barrier(0);
        stage(c + 3);
        compute((c & 3) * 32768);
    }
    WAIT_VM4();
    __builtin_amdgcn_s_barrier();
    __builtin_amdgcn_sched_barrier(0);
    compute((125 & 3) * 32768);
    WAIT_VM2();
    __builtin_amdgcn_s_barrier();
    __builtin_amdgcn_sched_barrier(0);
    compute((126 & 3) * 32768);
    WAIT_VM0();
    __builtin_amdgcn_s_barrier();
    __builtin_amdgcn_sched_barrier(0);
    compute((127 & 3) * 32768);

    // epilogue: OUT = acc + bias
    #pragma unroll
    for (int j = 0; j < 4; ++j) {
        const int n    = n0 + wc * 64 + j * 16 + l15;
        const float bv = BIAS[n];
        #pragma unroll
        for (int i = 0; i < 4; ++i) {
            const int mb = m0 + wr * 64 + i * 16 + (lhi << 2);
            #pragma unroll
            for (int t = 0; t < 4; ++t)
                OUT[(size_t)(mb + t) * N_DIM + n] = acc[i][j][t] + bv;
        }
    }
}

// ---------------- Fallback: round-1 fused kernel ----------------
__global__ void __launch_bounds__(256) gptq_gemm_kernel(
    const float* __restrict__ X, const int* __restrict__ QW,
    const int* __restrict__ QZ, const float* __restrict__ SC,
    const float* __restrict__ BIAS, float* __restrict__ OUT)
{
    __shared__ __align__(16) unsigned char slds[32768];
    const int tid  = threadIdx.x;
    const int n0   = blockIdx.x * 128;
    const int m0   = blockIdx.y * 128;
    const int wave = tid >> 6;
    const int lane = tid & 63;
    const int wm   = (wave >> 1) * 64;
    const int wn   = (wave & 1) * 64;
    const int l15  = lane & 15;
    const int lhi  = lane >> 4;
    const int arow  = tid >> 4;
    const int acol4 = (tid & 15) << 2;
    const int bnl   = tid & 127;
    const int brb   = tid >> 7;
    const int col   = n0 + bnl;

    f32x4 acc[4][4] = {};
    for (int kt = 0; kt < K_DIM / 64; ++kt) {
        const int k0 = kt * 64;
        #pragma unroll
        for (int r8 = 0; r8 < 8; ++r8) {
            const int row = (r8 << 4) + arow;
            f32x4 v = *reinterpret_cast<const f32x4*>(
                X + (size_t)(m0 + row) * K_DIM + (k0 + acol4));
            u16x4 h;
            #pragma unroll
            for (int e = 0; e < 4; ++e) h[e] = f2bf(v[e]);
            const int bo = row * 128 + ((acol4 << 1) ^ ((row & 7) << 4));
            *reinterpret_cast<u16x4*>(slds + bo) = h;
        }
        {
            const int g    = k0 >> 7;
            const int zp   = (((unsigned)QZ[g * (N_DIM / 8) + (col >> 3)])
                              >> ((col & 7) << 2)) & 15;
            const float sc = SC[g * N_DIM + col];
            const float zs = (float)zp * sc;
            #pragma unroll
            for (int rb = 0; rb < 4; ++rb) {
                const int rl = (rb << 1) + brb;
                const unsigned qw =
                    (unsigned)QW[(size_t)((k0 >> 3) + rl) * N_DIM + col];
                u16x8 h;
                #pragma unroll
                for (int j = 0; j < 8; ++j) {
                    float w = (float)((qw >> (j << 2)) & 15u) * sc - zs;
                    h[j] = f2bf(w);
                }
                const int bo = 16384 + bnl * 128 + ((rl << 4) ^ ((bnl & 7) << 4));
                *reinterpret_cast<u16x8*>(slds + bo) = h;
            }
        }
        __syncthreads();
        #pragma unroll
        for (int kk = 0; kk < 2; ++kk) {
            bf16x8 afr[4], bfr[4];
            #pragma unroll
            for (int i = 0; i < 4; ++i) {
                const int row = wm + (i << 4) + l15;
                afr[i] = *reinterpret_cast<const bf16x8*>(
                    slds + row * 128 + (((kk << 6) + (lhi << 4)) ^ ((row & 7) << 4)));
            }
            #pragma unroll
            for (int j = 0; j < 4; ++j) {
                const int n = wn + (j << 4) + l15;
                bfr[j] = *reinterpret_cast<const bf16x8*>(
                    slds + 16384 + n * 128 + (((kk << 6) + (lhi << 4)) ^ ((n & 7) << 4)));
            }
            #pragma unroll
            for (int i = 0; i < 4; ++i)
                #pragma unroll
                for (int j = 0; j < 4; ++j)
                    acc[i][j] = __builtin_amdgcn_mfma_f32_16x16x32_bf16(
                        afr[i], bfr[j], acc[i][j], 0, 0, 0);
        }
        __syncthreads();
    }
    #pragma unroll
    for (int j = 0; j < 4; ++j) {
        const int n    = n0 + wn + (j << 4) + l15;
        const float bv = BIAS[n];
        #pragma unroll
        for (int i = 0; i < 4; ++i) {
            const int mb = m0 + wm + (i << 4) + (lhi << 2);
            #pragma unroll
            for (int t = 0; t < 4; ++t)
                OUT[(size_t)(mb + t) * N_DIM + n] = acc[i][j][t] + bv;
        }
    }
}

extern "C" void kernel_launch(void* const* d_in, const int* in_sizes, int n_in,
                              void* d_out, int out_size, void* d_ws, size_t ws_size,
                              hipStream_t stream) {
    const float* X  = (const float*)d_in[0];
    const int*   QW = (const int*)d_in[1];
    const int*   QZ = (const int*)d_in[2];
    const float* SC = (const float*)d_in[3];
    const float* BI = (const float*)d_in[4];
    float*      OUT = (float*)d_out;

    const size_t xbf_bytes = (size_t)M_DIM * K_DIM * 2;
    const size_t wt_bytes  = (size_t)N_DIM * K_DIM * 2;

    if (ws_size >= xbf_bytes + wt_bytes) {
        __hip_bfloat16* Xbf = (__hip_bfloat16*)d_ws;
        __hip_bfloat16* Wt  = (__hip_bfloat16*)((char*)d_ws + xbf_bytes);

        cvt_x_kernel<<<(M_DIM * K_DIM) / (256 * 8), 256, 0, stream>>>(X, Xbf);
        dequant_kernel<<<dim3(N_DIM / 64, K_DIM / 256), 256, 0, stream>>>(QW, QZ, SC, Wt);
        gemm_bf16_kernel<<<dim3((M_DIM / 256) * (N_DIM / 256)), 1024, 131072, stream>>>(
            Xbf, Wt, BI, OUT);
    } else {
        gptq_gemm_kernel<<<dim3(N_DIM / 128, M_DIM / 128), 256, 0, stream>>>(
            X, QW, QZ, SC, BI, OUT);
    }
}